// Round 4
// baseline (176.551 us; speedup 1.0000x reference)
//
#include <hip/hip_runtime.h>
#include <hip/hip_bf16.h>

#define N 8192
#define D 128
#define NJS 8    // j-splits: each block covers 8 tiles of 128 cols
#define NPART (NJS * 2)  // partial slabs: (js, wn) pairs — waves must NOT share a slot
#define LN2 0.69314718056f

typedef __bf16 bf16x8 __attribute__((ext_vector_type(8)));
typedef float f32x4 __attribute__((ext_vector_type(4)));

// Kernel 1: row-normalize features (fp32 -> bf16), pre-scale by rsqrt(T*ln2)
// so that downstream acc = logits * log2(e); build label histogram.
__global__ void k_norm(const float* __restrict__ feat, const int* __restrict__ lab,
                       const float* __restrict__ tempp,
                       __hip_bfloat16* __restrict__ fbf, float* __restrict__ hist) {
    const int row  = blockIdx.x * 4 + (threadIdx.x >> 6);
    const int lane = threadIdx.x & 63;
    float2 v = *reinterpret_cast<const float2*>(&feat[row * D + lane * 2]);
    float ss = v.x * v.x + v.y * v.y;
#pragma unroll
    for (int m = 32; m; m >>= 1) ss += __shfl_xor(ss, m);
    const float sc = rsqrtf(tempp[0] * LN2);
    const float r = sc / fmaxf(sqrtf(ss), 1e-8f);
    __hip_bfloat162 o;
    o.x = __float2bfloat16(v.x * r);
    o.y = __float2bfloat16(v.y * r);
    *reinterpret_cast<__hip_bfloat162*>(&fbf[row * D + lane * 2]) = o;
    if (lane == 0) atomicAdd(&hist[lab[row]], 1.0f);  // integer counts: exact
}

// Kernel 2: A-register-resident fused GEMM + contrastive epilogue.
// Block (ib,js): rows [ib*128,+128), loops over 8 col-tiles of 128.
// Pipeline: per half-tile {32 MFMA -> issue next half's 8 B-loads -> epilogue}
// so the ~450cy epilogue hides L2 latency. Per-row ps/es accumulate in
// registers across all 8 tiles; single shuffle-reduce at block end.
// NOTE: waves wn=0/1 cover the SAME rows, different cols -> each writes its
// OWN partial slab (js*2+wn); R3's shared write was the ln2 bug.
__launch_bounds__(256, 2)
__global__ void k_gemm(const __hip_bfloat16* __restrict__ fbf,
                       const int* __restrict__ lab,
                       float* __restrict__ Pspos, float* __restrict__ Pedem) {
    const int ib = blockIdx.x, js = blockIdx.y;   // x fast => XCD = ib%8 (A stays hot)
    const int i0 = ib * 128;
    const int tid = threadIdx.x;
    const int wave = tid >> 6, lane = tid & 63;
    const int wm = wave >> 1, wn = wave & 1;      // 2x2 waves, 64x64 each
    const int lr = lane & 15, lg = lane >> 4;

    // A fragments: rows i0 + wm*64 + mi*16 + lr, k = ks*32 + lg*8 (resident)
    const __hip_bfloat16* pa = fbf + (size_t)(i0 + wm * 64 + lr) * D + lg * 8;
    bf16x8 af[4][4];
#pragma unroll
    for (int mi = 0; mi < 4; ++mi)
#pragma unroll
        for (int ks = 0; ks < 4; ++ks)
            af[mi][ks] = *reinterpret_cast<const bf16x8*>(pa + mi * 16 * D + ks * 32);

    int4 labi[4];
#pragma unroll
    for (int mi = 0; mi < 4; ++mi)
        labi[mi] = *reinterpret_cast<const int4*>(&lab[i0 + wm * 64 + mi * 16 + lg * 4]);

    float rps[4][4] = {}, res_[4][4] = {};        // running per-row partials

    const int jwbase = js * (NJS * 128) + wn * 64;  // this wave's first col
    bf16x8 bb[2][2][4];                             // [parity][nih][ks]
    int labj[2][2];

    // prologue: load stage t2=0 (tile 0, col-half 0)
#pragma unroll
    for (int nih = 0; nih < 2; ++nih) {
        const __hip_bfloat16* pb = fbf + (size_t)(jwbase + nih * 16 + lr) * D + lg * 8;
#pragma unroll
        for (int ks = 0; ks < 4; ++ks)
            bb[0][nih][ks] = *reinterpret_cast<const bf16x8*>(pb + ks * 32);
        labj[0][nih] = lab[jwbase + nih * 16 + lr];
    }

#pragma unroll
    for (int t2 = 0; t2 < 2 * NJS; ++t2) {        // 8 tiles x 2 col-halves
        const int p = t2 & 1;
        // ---- 32 MFMAs on current half ----
        f32x4 acc[4][2] = {};
#pragma unroll
        for (int ks = 0; ks < 4; ++ks)
#pragma unroll
            for (int mi = 0; mi < 4; ++mi)
#pragma unroll
                for (int nih = 0; nih < 2; ++nih)
                    acc[mi][nih] = __builtin_amdgcn_mfma_f32_16x16x32_bf16(
                        af[mi][ks], bb[p][nih][ks], acc[mi][nih], 0, 0, 0);
        // ---- issue next half's loads (consumed next iteration) ----
        if (t2 < 2 * NJS - 1) {
            const int nt = t2 + 1;
            const int ncol = jwbase + (nt >> 1) * 128 + (nt & 1) * 32;
#pragma unroll
            for (int nih = 0; nih < 2; ++nih) {
                const __hip_bfloat16* pb =
                    fbf + (size_t)(ncol + nih * 16 + lr) * D + lg * 8;
#pragma unroll
                for (int ks = 0; ks < 4; ++ks)
                    bb[p ^ 1][nih][ks] = *reinterpret_cast<const bf16x8*>(pb + ks * 32);
                labj[p ^ 1][nih] = lab[ncol + nih * 16 + lr];
            }
        }
        // ---- epilogue accumulate (covers the loads' latency) ----
        // C/D layout (m89): col = lane&15, row = (lane>>4)*4 + reg
#pragma unroll
        for (int mi = 0; mi < 4; ++mi)
#pragma unroll
            for (int r = 0; r < 4; ++r) {
                const int li = reinterpret_cast<const int*>(&labi[mi])[r];
#pragma unroll
                for (int nih = 0; nih < 2; ++nih) {
                    float v = acc[mi][nih][r];     // = logits * log2(e)
                    bool same = (li == labj[p][nih]);
                    rps[mi][r]  += same ? v : 0.0f;
                    res_[mi][r] += same ? 0.0f : __builtin_amdgcn_exp2f(v);
                }
            }
    }

    // ---- once-per-block reduce across the 16 col lanes, then write ----
    const int slab = js * 2 + wn;                 // per-wave-column-half slab
#pragma unroll
    for (int mi = 0; mi < 4; ++mi)
#pragma unroll
        for (int r = 0; r < 4; ++r) {
            float ps = rps[mi][r], es = res_[mi][r];
#pragma unroll
            for (int m = 1; m < 16; m <<= 1) {
                ps += __shfl_xor(ps, m);
                es += __shfl_xor(es, m);
            }
            if (lr == 0) {
                const int rowl = wm * 64 + mi * 16 + lg * 4 + r;
                Pspos[slab * N + i0 + rowl] = ps;
                Pedem[slab * N + i0 + rowl] = es;
            }
        }
}

// Kernel 3: per-row combine over NPART slabs, then per-block partial sum.
__global__ void k_row(const float* __restrict__ Pspos, const float* __restrict__ Pedem,
                      const int* __restrict__ lab, const float* __restrict__ hist,
                      float* __restrict__ bsums) {
    const int i = blockIdx.x * 256 + threadIdx.x;
    float sp = 0.0f, ed = 0.0f;
#pragma unroll
    for (int s = 0; s < NPART; ++s) {
        sp += Pspos[s * N + i];
        ed += Pedem[s * N + i];
    }
    const float cnt = hist[lab[i]];
    float term = LN2 * (sp / cnt - __builtin_amdgcn_logf(ed));  // log2 -> ln via LN2
#pragma unroll
    for (int m = 32; m; m >>= 1) term += __shfl_xor(term, m);
    __shared__ float s4[4];
    if ((threadIdx.x & 63) == 0) s4[threadIdx.x >> 6] = term;
    __syncthreads();
    if (threadIdx.x == 0) bsums[blockIdx.x] = s4[0] + s4[1] + s4[2] + s4[3];
}

// Kernel 4: final scalar over 32 block sums.
__global__ void k_final(const float* __restrict__ bsums, float* __restrict__ out) {
    float v = (threadIdx.x < 32) ? bsums[threadIdx.x] : 0.0f;
#pragma unroll
    for (int m = 32; m; m >>= 1) v += __shfl_xor(v, m);
    if (threadIdx.x == 0) out[0] = -(v / (float)N);
}

extern "C" void kernel_launch(void* const* d_in, const int* in_sizes, int n_in,
                              void* d_out, int out_size, void* d_ws, size_t ws_size,
                              hipStream_t stream) {
    const float* feat = (const float*)d_in[0];
    const int* lab    = (const int*)d_in[1];
    const float* temp = (const float*)d_in[2];
    float* out = (float*)d_out;
    char* ws = (char*)d_ws;

    __hip_bfloat16* fbf = (__hip_bfloat16*)ws;      // 2 MB normalized+scaled bf16
    float* hist  = (float*)(ws + 2097152);          // 512 B label histogram
    float* Pspos = (float*)(ws + 2097664);          // 512 KB partials [16][8192]
    float* Pedem = (float*)(ws + 2621952);          // 512 KB partials [16][8192]
    float* bsums = (float*)(ws + 3146240);          // 128 B

    hipMemsetAsync(hist, 0, 128 * sizeof(float), stream);
    k_norm<<<N / 4, 256, 0, stream>>>(feat, lab, temp, fbf, hist);
    dim3 grid(N / 128, NJS);                        // x=ib fast -> XCD = ib%8
    k_gemm<<<grid, 256, 0, stream>>>(fbf, lab, Pspos, Pedem);
    k_row<<<N / 256, 256, 0, stream>>>(Pspos, Pedem, lab, hist, bsums);
    k_final<<<1, 64, 0, stream>>>(bsums, out);
}

// Round 5
// 61.785 us; speedup vs baseline: 2.8575x; 2.8575x over previous
//
#include <hip/hip_runtime.h>
#include <hip/hip_bf16.h>

#define N 8192
#define D 128
#define NJS 8           // j-tiles of 128 per block (block covers 1024 cols)
#define NPART (NJS * 2) // partial slabs: (js, wn)
#define LN2 0.69314718056f

typedef __bf16 bf16x8 __attribute__((ext_vector_type(8)));
typedef float f32x4 __attribute__((ext_vector_type(4)));
typedef unsigned int u32;

// async global->LDS, 16B per lane; LDS dest = wave-uniform base + lane*16,
// global src is per-lane (m173: swizzle lives on the SOURCE address).
__device__ __forceinline__ void gload_lds16(const void* g, void* l) {
    __builtin_amdgcn_global_load_lds(
        (const __attribute__((address_space(1))) u32*)g,
        (__attribute__((address_space(3))) u32*)l, 16, 0, 0);
}

// Kernel 1: row-normalize features (fp32 -> bf16), pre-scaled by rsqrt(T*ln2)
// so downstream acc = logits * log2(e).
__global__ void k_norm(const float* __restrict__ feat, const float* __restrict__ tempp,
                       __hip_bfloat16* __restrict__ fbf) {
    const int row  = blockIdx.x * 4 + (threadIdx.x >> 6);
    const int lane = threadIdx.x & 63;
    float2 v = *reinterpret_cast<const float2*>(&feat[row * D + lane * 2]);
    float ss = v.x * v.x + v.y * v.y;
#pragma unroll
    for (int m = 32; m; m >>= 1) ss += __shfl_xor(ss, m);
    const float sc = rsqrtf(tempp[0] * LN2);
    const float r = sc / fmaxf(sqrtf(ss), 1e-8f);
    __hip_bfloat162 o;
    o.x = __float2bfloat16(v.x * r);
    o.y = __float2bfloat16(v.y * r);
    *reinterpret_cast<__hip_bfloat162*>(&fbf[row * D + lane * 2]) = o;
}

// Kernel 2: A-register-resident, B via double-buffered LDS (global_load_lds).
// NO runtime-indexed register arrays (rule #20) — buffer parity selects an
// LDS *address* only. One barrier per tile; stage(t+1) issued before
// compute(t) so ~900cy of MFMA+exp hides the load latency.
__launch_bounds__(256, 2)
__global__ void k_gemm(const __hip_bfloat16* __restrict__ fbf,
                       const int* __restrict__ lab,
                       float* __restrict__ Pspos, float* __restrict__ Pedem) {
    __shared__ char Bs[65536];                    // 2 x 32KB B-tile buffers
    const int ib = blockIdx.x, js = blockIdx.y;   // linear id = ib + 64*js
    const int i0 = ib * 128;                      // -> XCD = ib%8: A L2-hot
    const int tid = threadIdx.x;
    const int wave = tid >> 6, lane = tid & 63;
    const int wm = wave >> 1, wn = wave & 1;      // 2x2 waves, 64x64 each
    const int lr = lane & 15, lg = lane >> 4;

    // A fragments resident: rows i0 + wm*64 + mi*16 + lr, k = ks*32 + lg*8
    const __hip_bfloat16* pa = fbf + (size_t)(i0 + wm * 64 + lr) * D + lg * 8;
    bf16x8 af[4][4];
#pragma unroll
    for (int mi = 0; mi < 4; ++mi)
#pragma unroll
        for (int ks = 0; ks < 4; ++ks)
            af[mi][ks] = *reinterpret_cast<const bf16x8*>(pa + mi * 16 * D + ks * 32);

    int4 labi[4];
#pragma unroll
    for (int mi = 0; mi < 4; ++mi)
        labi[mi] = *reinterpret_cast<const int4*>(&lab[i0 + wm * 64 + mi * 16 + lg * 4]);

    float rps[4][4] = {}, res_[4][4] = {};        // running per-row partials

    const char* fbytes = reinterpret_cast<const char*>(fbf);

    // Stage tile t into buffer (t&1). LDS linear chunk c holds global chunk
    // (row, (c&15) ^ (row&7)) — inverse of the read-side XOR (involution).
#define STAGE(t)                                                               \
    {                                                                          \
        const int j0s = js * (NJS * 128) + (t) * 128;                          \
        char* dst = Bs + ((t) & 1) * 32768;                                    \
        _Pragma("unroll")                                                      \
        for (int it = 0; it < 8; ++it) {                                       \
            const int base = (it * 4 + wave) * 64;                             \
            const int c = base + lane;                                         \
            const int row = c >> 4;                                            \
            const int kc = (c & 15) ^ (row & 7);                               \
            gload_lds16(fbytes + (size_t)(j0s + row) * 256 + kc * 16,          \
                        dst + base * 16);                                      \
        }                                                                      \
    }

    STAGE(0);
    __syncthreads();

    for (int t = 0; t < NJS; ++t) {
        if (t < NJS - 1) STAGE(t + 1);
        const char* buf = Bs + (t & 1) * 32768;
        const int j0 = js * (NJS * 128) + t * 128;
#pragma unroll
        for (int h = 0; h < 2; ++h) {             // two 32-col halves per tile
            bf16x8 bfr[2][4];
#pragma unroll
            for (int nih = 0; nih < 2; ++nih)
#pragma unroll
                for (int ks = 0; ks < 4; ++ks) {
                    const int R = wn * 64 + h * 32 + nih * 16 + lr;
                    const int kc = ks * 4 + lg;
                    bfr[nih][ks] = *reinterpret_cast<const bf16x8*>(
                        buf + R * 256 + ((kc ^ (R & 7)) << 4));
                }
            f32x4 acc[4][2] = {};
#pragma unroll
            for (int ks = 0; ks < 4; ++ks)
#pragma unroll
                for (int mi = 0; mi < 4; ++mi)
#pragma unroll
                    for (int nih = 0; nih < 2; ++nih)
                        acc[mi][nih] = __builtin_amdgcn_mfma_f32_16x16x32_bf16(
                            af[mi][ks], bfr[nih][ks], acc[mi][nih], 0, 0, 0);
            int labj[2];
            labj[0] = lab[j0 + wn * 64 + h * 32 + lr];
            labj[1] = lab[j0 + wn * 64 + h * 32 + 16 + lr];
            // C/D layout (m89): col = lane&15, row = (lane>>4)*4 + reg
#pragma unroll
            for (int mi = 0; mi < 4; ++mi)
#pragma unroll
                for (int r = 0; r < 4; ++r) {
                    const int li = reinterpret_cast<const int*>(&labi[mi])[r];
#pragma unroll
                    for (int nih = 0; nih < 2; ++nih) {
                        float v = acc[mi][nih][r];   // = logits * log2(e)
                        bool same = (li == labj[nih]);
                        rps[mi][r]  += same ? v : 0.0f;
                        res_[mi][r] += same ? 0.0f : __builtin_amdgcn_exp2f(v);
                    }
                }
        }
        __syncthreads();   // waves done reading buf(t&1); stage(t+1) landed
    }

    // once-per-block reduce across the 16 col lanes, write per-(js,wn) slab
    const int slab = js * 2 + wn;
#pragma unroll
    for (int mi = 0; mi < 4; ++mi)
#pragma unroll
        for (int r = 0; r < 4; ++r) {
            float ps = rps[mi][r], es = res_[mi][r];
#pragma unroll
            for (int m = 1; m < 16; m <<= 1) {
                ps += __shfl_xor(ps, m);
                es += __shfl_xor(es, m);
            }
            if (lr == 0) {
                const int rowl = wm * 64 + mi * 16 + lg * 4 + r;
                Pspos[slab * N + i0 + rowl] = ps;
                Pedem[slab * N + i0 + rowl] = es;
            }
        }
#undef STAGE
}

// Kernel 3 (fused tail, 1 block x 1024): LDS label histogram, per-row
// combine over 16 slabs, block-reduce, final scalar.
__global__ void k_tail(const float* __restrict__ Pspos, const float* __restrict__ Pedem,
                       const int* __restrict__ lab, float* __restrict__ out) {
    __shared__ float hist[128];
    __shared__ float wsum[16];
    const int tid = threadIdx.x;
    if (tid < 128) hist[tid] = 0.0f;
    __syncthreads();
#pragma unroll
    for (int k = 0; k < 8; ++k) atomicAdd(&hist[lab[tid + k * 1024]], 1.0f);
    __syncthreads();
    float sum = 0.0f;
#pragma unroll
    for (int k = 0; k < 8; ++k) {
        const int i = tid + k * 1024;
        float sp = 0.0f, ed = 0.0f;
#pragma unroll
        for (int s = 0; s < NPART; ++s) {
            sp += Pspos[s * N + i];
            ed += Pedem[s * N + i];
        }
        const float cnt = hist[lab[i]];
        sum += LN2 * (sp / cnt - __builtin_amdgcn_logf(ed));  // log2 -> ln
    }
#pragma unroll
    for (int m = 32; m; m >>= 1) sum += __shfl_xor(sum, m);
    if ((tid & 63) == 0) wsum[tid >> 6] = sum;
    __syncthreads();
    if (tid < 64) {
        float v = (tid < 16) ? wsum[tid] : 0.0f;
#pragma unroll
        for (int m = 32; m; m >>= 1) v += __shfl_xor(v, m);
        if (tid == 0) out[0] = -(v / (float)N);
    }
}

extern "C" void kernel_launch(void* const* d_in, const int* in_sizes, int n_in,
                              void* d_out, int out_size, void* d_ws, size_t ws_size,
                              hipStream_t stream) {
    const float* feat = (const float*)d_in[0];
    const int* lab    = (const int*)d_in[1];
    const float* temp = (const float*)d_in[2];
    float* out = (float*)d_out;
    char* ws = (char*)d_ws;

    __hip_bfloat16* fbf = (__hip_bfloat16*)ws;      // 2 MB normalized+scaled bf16
    float* Pspos = (float*)(ws + 2097152);          // 512 KB partials [16][8192]
    float* Pedem = (float*)(ws + 2621440);          // 512 KB partials [16][8192]

    k_norm<<<N / 4, 256, 0, stream>>>(feat, temp, fbf);
    dim3 grid(N / 128, NJS);                        // x=ib fast -> XCD = ib%8
    k_gemm<<<grid, 256, 0, stream>>>(fbf, lab, Pspos, Pedem);
    k_tail<<<1, 1024, 0, stream>>>(Pspos, Pedem, lab, out);
}